// Round 6
// baseline (248.897 us; speedup 1.0000x reference)
//
#include <hip/hip_runtime.h>
#include <hip/hip_cooperative_groups.h>

namespace cg = cooperative_groups;

#define EPS_C 0.05f
#define BLOCK 256
#define BPB   32768            /* elems per block (fused path) */
#define NB    1024             /* 4 blocks/CU x 256 CU = exactly co-resident */

typedef int i4 __attribute__((ext_vector_type(4)));
typedef float f4 __attribute__((ext_vector_type(4)));

// Build the 6-entry change table into LDS (thread 0 only; caller syncs).
__device__ __forceinline__ void build_table(const float* bd_p, const float* d_p,
                                            const float* s_p, const float* inc_p,
                                            const float* bi_p, float* cs) {
  if (threadIdx.x == 0) {
    float bd = *bd_p, d = *d_p, s = *s_p, inc = *inc_p, bi = *bi_p;
    cs[0] = 0.0f;                                   // cat 0 (unused)
    cs[1] = fminf(bd, fminf(0.0f, d)) - EPS_C;      // big decrease
    cs[2] = fminf(fmaxf(d, bd + EPS_C), -EPS_C);    // decrease (clip)
    cs[3] = s;                                      // same
    cs[4] = fminf(fmaxf(inc, EPS_C), bi - EPS_C);   // increase (clip)
    cs[5] = fmaxf(bi, fmaxf(0.0f, inc) + EPS_C);    // big increase
    cs[6] = 0.0f; cs[7] = 0.0f;
  }
}

// Fused single-pass scan (cooperative). See R4 notes: phase A pack-in-regs +
// block sums, grid.sync, phase B coarse prefix (<=4 iters), phase C decode+
// scan+NT store. 1024 blocks x 256 thr, launch_bounds(256,4) => co-resident.
__global__ __launch_bounds__(BLOCK, 4) void k_fused(
    const int* __restrict__ ann, const float* __restrict__ origin,
    const float* bd, const float* d, const float* s, const float* inc,
    const float* bi, float* __restrict__ out, float* __restrict__ coarse,
    int nb) {
  __shared__ float cs[8];
  __shared__ float wsum[4];   // per-wave totals (phase A; reused in C)
  __shared__ float ws2[4];    // coarse-prefix partials (phase B)
  __shared__ float s_excl;    // origin + sum coarse[0..b)
  const int t = threadIdx.x, lane = t & 63, w = t >> 6, b = blockIdx.x;

  build_table(bd, d, s, inc, bi, cs);
  __syncthreads();

  // ---- phase A ----
  const size_t ebase = (size_t)b * BPB + (size_t)w * 8192;
  const i4* in4 = (const i4*)ann + (ebase >> 2) + lane;
  unsigned pk[16];            // 32 nibble-packed ushorts, element order
  float usum[8];              // per-1024-unit sums (full sum in ALL lanes)
#pragma unroll
  for (int u = 0; u < 8; ++u) {
    float sum = 0.0f;
#pragma unroll
    for (int r = 0; r < 4; ++r) {
      i4 v = __builtin_nontemporal_load(&in4[u * 256 + r * 64]);
      sum += cs[v.x] + cs[v.y] + cs[v.z] + cs[v.w];
      unsigned nib = (unsigned)v.x | ((unsigned)v.y << 4) |
                     ((unsigned)v.z << 8) | ((unsigned)v.w << 12);
      if (r & 1) pk[u * 2 + (r >> 1)] |= nib << 16;
      else       pk[u * 2 + (r >> 1)]  = nib;
    }
#pragma unroll
    for (int off = 32; off >= 1; off >>= 1) sum += __shfl_xor(sum, off, 64);
    usum[u] = sum;
  }
  float wtot = 0.0f;
#pragma unroll
  for (int u = 0; u < 8; ++u) wtot += usum[u];
  if (lane == 0) wsum[w] = wtot;
  __syncthreads();
  if (t == 0) {
    float bt = wsum[0] + wsum[1] + wsum[2] + wsum[3];
    __hip_atomic_store(&coarse[b], bt, __ATOMIC_RELEASE,
                       __HIP_MEMORY_SCOPE_AGENT);   // cross-XCD visible
  }

  cg::this_grid().sync();

  // ---- phase B: block-exclusive prefix over coarse[0..b) ----
  float p = 0.0f;
  for (int i = t; i < b; i += BLOCK)
    p += __hip_atomic_load(&coarse[i], __ATOMIC_RELAXED,
                           __HIP_MEMORY_SCOPE_AGENT);
#pragma unroll
  for (int off = 32; off >= 1; off >>= 1) p += __shfl_xor(p, off, 64);
  if (lane == 0) ws2[w] = p;
  __syncthreads();
  if (t == 0) {
    float e = *origin + ws2[0] + ws2[1] + ws2[2] + ws2[3];
    s_excl = e;
    if (b == nb - 1)    // out[N] = origin + grand total
      out[(size_t)nb * BPB] = e + wsum[0] + wsum[1] + wsum[2] + wsum[3];
  }
  __syncthreads();

  // ---- phase C: decode + scan + NT store (no further barriers) ----
  float carry = s_excl;
  if (w > 0) carry += wsum[0];
  if (w > 1) carry += wsum[1];
  if (w > 2) carry += wsum[2];
#pragma unroll
  for (int u = 0; u < 8; ++u) {
    float c2 = carry;
#pragma unroll
    for (int r = 0; r < 4; ++r) {
      const unsigned pw = pk[u * 2 + (r >> 1)];
      const unsigned us = (r & 1) ? (pw >> 16) : (pw & 0xFFFFu);
      const float v0 = cs[us & 0xFu];
      const float v1 = cs[(us >> 4) & 0xFu];
      const float v2 = cs[(us >> 8) & 0xFu];
      const float v3 = cs[(us >> 12) & 0xFu];
      const float s4 = v0 + v1 + v2 + v3;
      float x = s4;                    // inclusive wave scan of 4-elem sums
#pragma unroll
      for (int off = 1; off < 64; off <<= 1) {
        float y = __shfl_up(x, off, 64);
        if (lane >= off) x += y;
      }
      const float off0 = c2 + (x - s4);
      f4 o;
      o.x = off0;
      o.y = off0 + v0;
      o.z = o.y + v1;
      o.w = o.z + v2;
      __builtin_nontemporal_store(
          o, (f4*)(out + ebase + u * 1024 + r * 256 + lane * 4));
      c2 += __shfl(x, 63, 64);         // round total
    }
    carry += usum[u];                  // unit total (exact, all lanes)
  }
}

/* ---------------- fallback: proven R4 3-kernel path ---------------- */

__global__ __launch_bounds__(256) void k_pack_reduce(
    const int* __restrict__ ann, const float* bd, const float* d,
    const float* s, const float* inc, const float* bi,
    unsigned short* __restrict__ pack, float* __restrict__ fine) {
  __shared__ float cs[8];
  build_table(bd, d, s, inc, bi, cs);
  __syncthreads();
  const int t = threadIdx.x, lane = t & 63, w = t >> 6, b = blockIdx.x;
  const size_t ebase = (size_t)b * 8192 + w * 2048;
  const i4* in4 = (const i4*)ann + (ebase >> 2) + lane;
  unsigned short* pkp = pack + (ebase >> 2) + lane;
  float fs0 = 0.0f, fs1 = 0.0f;
#pragma unroll
  for (int r = 0; r < 8; ++r) {
    i4 v = __builtin_nontemporal_load(&in4[r * 64]);
    float e = cs[v.x] + cs[v.y] + cs[v.z] + cs[v.w];
    if (r < 4) fs0 += e; else fs1 += e;
    unsigned us = (unsigned)v.x | ((unsigned)v.y << 4) |
                  ((unsigned)v.z << 8) | ((unsigned)v.w << 12);
    pkp[r * 64] = (unsigned short)us;
  }
#pragma unroll
  for (int off = 32; off >= 1; off >>= 1) {
    fs0 += __shfl_xor(fs0, off, 64);
    fs1 += __shfl_xor(fs1, off, 64);
  }
  if (lane == 0) {
    fine[b * 8 + w * 2 + 0] = fs0;
    fine[b * 8 + w * 2 + 1] = fs1;
  }
}

__global__ __launch_bounds__(1024) void k_scan_fine(
    const float* __restrict__ fine, const float* __restrict__ origin,
    float* __restrict__ pref, float* __restrict__ outN) {
  __shared__ float ws[16];
  const int t = threadIdx.x, lane = t & 63, w = t >> 6;
  float v[32];
  const f4* fv = (const f4*)fine + t * 8;
  float tot = 0.0f;
#pragma unroll
  for (int i = 0; i < 8; ++i) {
    f4 x = fv[i];
    v[i * 4 + 0] = x.x; v[i * 4 + 1] = x.y;
    v[i * 4 + 2] = x.z; v[i * 4 + 3] = x.w;
    tot += x.x + x.y + x.z + x.w;
  }
  float x = tot;
#pragma unroll
  for (int off = 1; off < 64; off <<= 1) {
    float y = __shfl_up(x, off, 64);
    if (lane >= off) x += y;
  }
  if (lane == 63) ws[w] = x;
  __syncthreads();
  float wexcl = 0.0f;
#pragma unroll
  for (int i = 0; i < 16; ++i) { float wv = ws[i]; if (i < w) wexcl += wv; }
  float run = *origin + wexcl + (x - tot);
#pragma unroll
  for (int i = 0; i < 8; ++i) {
    f4 o;
    o.x = run; run += v[i * 4 + 0];
    o.y = run; run += v[i * 4 + 1];
    o.z = run; run += v[i * 4 + 2];
    o.w = run; run += v[i * 4 + 3];
    ((f4*)pref)[t * 8 + i] = o;
  }
  if (t == 1023) *outN = run;
}

__global__ __launch_bounds__(256) void k_scan_out(
    const unsigned short* __restrict__ pack, const float* __restrict__ pref,
    const float* bd, const float* d, const float* s, const float* inc,
    const float* bi, float* __restrict__ out) {
  __shared__ float cs[8];
  build_table(bd, d, s, inc, bi, cs);
  __syncthreads();
  const int t = threadIdx.x, lane = t & 63, w = t >> 6, b = blockIdx.x;
#pragma unroll
  for (int h = 0; h < 2; ++h) {
    const int u = b * 8 + w * 2 + h;
    const size_t ebase = (size_t)u * 1024;
    const unsigned short* pkp = pack + (ebase >> 2) + lane;
    unsigned short usv[4] = {pkp[0], pkp[64], pkp[128], pkp[192]};
    float carry = pref[u];
#pragma unroll
    for (int r = 0; r < 4; ++r) {
      const unsigned us = usv[r];
      const float v0 = cs[us & 0xFu];
      const float v1 = cs[(us >> 4) & 0xFu];
      const float v2 = cs[(us >> 8) & 0xFu];
      const float v3 = cs[(us >> 12) & 0xFu];
      const float s4 = v0 + v1 + v2 + v3;
      float x = s4;
#pragma unroll
      for (int off = 1; off < 64; off <<= 1) {
        float y = __shfl_up(x, off, 64);
        if (lane >= off) x += y;
      }
      const float off0 = carry + (x - s4);
      f4 o;
      o.x = off0;
      o.y = off0 + v0;
      o.z = o.y + v1;
      o.w = o.z + v2;
      __builtin_nontemporal_store(o, (f4*)(out + ebase + r * 256 + lane * 4));
      carry += __shfl(x, 63, 64);
    }
  }
}

extern "C" void kernel_launch(void* const* d_in, const int* in_sizes, int n_in,
                              void* d_out, int out_size, void* d_ws, size_t ws_size,
                              hipStream_t stream) {
  const int*   ann    = (const int*)d_in[0];
  const float* origin = (const float*)d_in[1];
  const float* bd     = (const float*)d_in[2];
  const float* dw     = (const float*)d_in[3];
  const float* sw     = (const float*)d_in[4];
  const float* ic     = (const float*)d_in[5];
  const float* bi     = (const float*)d_in[6];
  float* out = (float*)d_out;

  const int N = in_sizes[0];          // 2^25 = NB * BPB

  float* coarse = (float*)d_ws;       // NB floats

  if (N == NB * BPB) {
    // Guard: verify true co-residency before trusting grid.sync (pure query,
    // graph-capture-safe). Needs >= 4 blocks/CU so 1024 blocks all resident.
    int maxb = 0;
    hipError_t qe = hipOccupancyMaxActiveBlocksPerMultiprocessor(
        &maxb, (const void*)k_fused, BLOCK, 0);
    if (qe == hipSuccess && maxb >= 4) {
      int nb = NB;
      void* args[] = {(void*)&ann, (void*)&origin, (void*)&bd, (void*)&dw,
                      (void*)&sw, (void*)&ic, (void*)&bi, (void*)&out,
                      (void*)&coarse, (void*)&nb};
      hipError_t e = hipLaunchCooperativeKernel((const void*)k_fused, dim3(NB),
                                                dim3(BLOCK), args, 0, stream);
      if (e == hipSuccess) return;
      // else fall through to the 3-kernel path
    }
  }

  const int nbc = N / 8192;
  const int nf  = N / 1024;
  float* fine = (float*)d_ws + 4096;                    // past coarse
  float* pref = fine + nf;
  unsigned short* pack = (unsigned short*)(pref + nf);

  k_pack_reduce<<<nbc, 256, 0, stream>>>(ann, bd, dw, sw, ic, bi, pack, fine);
  k_scan_fine<<<1, 1024, 0, stream>>>(fine, origin, pref, out + N);
  k_scan_out<<<nbc, 256, 0, stream>>>(pack, pref, bd, dw, sw, ic, bi, out);
}

// Round 7
// 241.075 us; speedup vs baseline: 1.0324x; 1.0324x over previous
//
#include <hip/hip_runtime.h>

#define EPS_C 0.05f
#define BLOCK 256
#define BPB   8192    /* elems per block, both kernels: 4 waves x 2 units */

typedef int i4 __attribute__((ext_vector_type(4)));
typedef float f4 __attribute__((ext_vector_type(4)));
typedef unsigned int u2 __attribute__((ext_vector_type(2)));

// Build the 6-entry change table into LDS (thread 0 only; caller syncs).
__device__ __forceinline__ void build_table(const float* bd_p, const float* d_p,
                                            const float* s_p, const float* inc_p,
                                            const float* bi_p, float* cs) {
  if (threadIdx.x == 0) {
    float bd = *bd_p, d = *d_p, s = *s_p, inc = *inc_p, bi = *bi_p;
    cs[0] = 0.0f;                                   // cat 0 (unused)
    cs[1] = fminf(bd, fminf(0.0f, d)) - EPS_C;      // big decrease
    cs[2] = fminf(fmaxf(d, bd + EPS_C), -EPS_C);    // decrease (clip)
    cs[3] = s;                                      // same
    cs[4] = fminf(fmaxf(inc, EPS_C), bi - EPS_C);   // increase (clip)
    cs[5] = fmaxf(bi, fmaxf(0.0f, inc) + EPS_C);    // big increase
    cs[6] = 0.0f; cs[7] = 0.0f;
  }
}

// K1: block b owns 8192 elems (4 waves x 2 units x 1024). Per unit, lane l
// accumulates rounds r=0..3 (elems ubase + r*256 + 4l) into one uint2 nibble
// pack -> ONE coalesced 8B store per unit (512B/wave). Emits per-unit fine
// sums and the block sum coarse[b]. Input loads NT (read-once).
__global__ __launch_bounds__(BLOCK) void k_pack_reduce(
    const int* __restrict__ ann, const float* bd, const float* d,
    const float* s, const float* inc, const float* bi,
    u2* __restrict__ pack, float* __restrict__ coarse,
    float* __restrict__ fine) {
  __shared__ float cs[8];
  __shared__ float wsum[4];
  build_table(bd, d, s, inc, bi, cs);
  __syncthreads();
  const int t = threadIdx.x, lane = t & 63, w = t >> 6, b = blockIdx.x;
  const size_t ebase = (size_t)b * BPB + (size_t)w * 2048;  // wave's first elem
  const i4* in4 = (const i4*)ann + (ebase >> 2) + lane;
  float fs[2];
#pragma unroll
  for (int u = 0; u < 2; ++u) {
    unsigned lo = 0, hi = 0;
    float sum = 0.0f;
#pragma unroll
    for (int r = 0; r < 4; ++r) {
      i4 v = __builtin_nontemporal_load(&in4[u * 256 + r * 64]);
      sum += cs[v.x] + cs[v.y] + cs[v.z] + cs[v.w];
      unsigned nib = (unsigned)v.x | ((unsigned)v.y << 4) |
                     ((unsigned)v.z << 8) | ((unsigned)v.w << 12);
      if (r & 1) { if (r < 2) lo |= nib << 16; else hi |= nib << 16; }
      else       { if (r < 2) lo |= nib;       else hi |= nib; }
    }
    // unit id = b*8 + w*2 + u; slot = unit*64 + lane (cached store: K2 re-reads via L3)
    pack[((size_t)b * 8 + w * 2 + u) * 64 + lane] = (u2){lo, hi};
#pragma unroll
    for (int off = 32; off >= 1; off >>= 1) sum += __shfl_xor(sum, off, 64);
    fs[u] = sum;
  }
  if (lane == 0) {
    fine[b * 8 + w * 2 + 0] = fs[0];
    fine[b * 8 + w * 2 + 1] = fs[1];
    wsum[w] = fs[0] + fs[1];
  }
  __syncthreads();
  if (t == 0) coarse[b] = wsum[0] + wsum[1] + wsum[2] + wsum[3];
}

// K2: block b owns the same 8192 elems. Pack prefetch (uint2/unit) issues
// first and hides under the coarse-prefix loop (<=16 L2/L3-hot iters/thread).
// One __syncthreads total; decode/scan/store tail is barrier-free.
__global__ __launch_bounds__(BLOCK) void k_scan_out(
    const u2* __restrict__ pack, const float* __restrict__ coarse,
    const float* __restrict__ fine, const float* __restrict__ origin,
    const float* bd, const float* d, const float* s, const float* inc,
    const float* bi, float* __restrict__ out, int nb) {
  __shared__ float cs[8];
  __shared__ float ws2[4];
  build_table(bd, d, s, inc, bi, cs);
  const int t = threadIdx.x, lane = t & 63, w = t >> 6, b = blockIdx.x;

  // prefetch both units' packs (in flight during the offset work)
  const u2 pk0 = pack[((size_t)b * 8 + w * 2 + 0) * 64 + lane];
  const u2 pk1 = pack[((size_t)b * 8 + w * 2 + 1) * 64 + lane];

  // block-exclusive prefix over coarse[0..b)
  float p = 0.0f;
  for (int i = t; i < b; i += BLOCK) p += coarse[i];
#pragma unroll
  for (int off = 32; off >= 1; off >>= 1) p += __shfl_xor(p, off, 64);
  if (lane == 0) ws2[w] = p;
  __syncthreads();                       // covers cs[] and ws2[]
  const float P = *origin + ws2[0] + ws2[1] + ws2[2] + ws2[3];

  // in-block unit offsets: inclusive 8-lane shfl scan of fine[b*8..+8)
  float f = (lane < 8) ? fine[b * 8 + lane] : 0.0f;
#pragma unroll
  for (int off = 1; off < 8; off <<= 1) {
    float y = __shfl_up(f, off, 64);
    if (lane >= off && lane < 8) f += y;
  }
  if (b == nb - 1 && w == 0 && lane == 7)
    out[(size_t)nb * BPB] = P + f;       // out[N] = origin + grand total

  const u2 pks[2] = {pk0, pk1};
#pragma unroll
  for (int h = 0; h < 2; ++h) {
    const int j = w * 2 + h;             // unit index within block
    float carry = P + ((j > 0) ? __shfl(f, j - 1, 64) : 0.0f);
    const u2 pk = pks[h];
    const size_t ubase = (size_t)b * BPB + (size_t)j * 1024;
#pragma unroll
    for (int r = 0; r < 4; ++r) {
      const unsigned pw = (r < 2) ? pk.x : pk.y;
      const unsigned us = (r & 1) ? (pw >> 16) : (pw & 0xFFFFu);
      const float v0 = cs[us & 0xFu];
      const float v1 = cs[(us >> 4) & 0xFu];
      const float v2 = cs[(us >> 8) & 0xFu];
      const float v3 = cs[(us >> 12) & 0xFu];
      const float s4 = v0 + v1 + v2 + v3;
      float x = s4;                      // inclusive wave scan of 4-elem sums
#pragma unroll
      for (int off = 1; off < 64; off <<= 1) {
        float y = __shfl_up(x, off, 64);
        if (lane >= off) x += y;
      }
      const float off0 = carry + (x - s4);
      f4 o;
      o.x = off0;
      o.y = off0 + v0;
      o.z = o.y + v1;
      o.w = o.z + v2;
      __builtin_nontemporal_store(o, (f4*)(out + ubase + r * 256 + lane * 4));
      carry += __shfl(x, 63, 64);        // round total -> next round
    }
  }
}

extern "C" void kernel_launch(void* const* d_in, const int* in_sizes, int n_in,
                              void* d_out, int out_size, void* d_ws, size_t ws_size,
                              hipStream_t stream) {
  const int*   ann    = (const int*)d_in[0];
  const float* origin = (const float*)d_in[1];
  const float* bd     = (const float*)d_in[2];
  const float* dw     = (const float*)d_in[3];
  const float* sw     = (const float*)d_in[4];
  const float* ic     = (const float*)d_in[5];
  const float* bi     = (const float*)d_in[6];
  float* out = (float*)d_out;

  const int N  = in_sizes[0];   // 2^25
  const int nb = N / BPB;       // 4096 blocks

  float* coarse = (float*)d_ws;                 // 4096 floats
  float* fine   = coarse + 4096;                // 32768 floats
  u2*    pack   = (u2*)(fine + 32768);          // 16.8 MB

  k_pack_reduce<<<nb, BLOCK, 0, stream>>>(ann, bd, dw, sw, ic, bi,
                                          pack, coarse, fine);
  k_scan_out<<<nb, BLOCK, 0, stream>>>(pack, coarse, fine, origin,
                                       bd, dw, sw, ic, bi, out, nb);
}